// Round 2
// baseline (75092.432 us; speedup 1.0000x reference)
//
#include <hip/hip_runtime.h>
#include <hip/hip_bf16.h>
#include <stdint.h>

#define VV 8192
#define HH 1024
#define TT 256
#define BB 64

typedef __attribute__((ext_vector_type(4))) float f32x4;
typedef __attribute__((ext_vector_type(8))) short bf16x8;

// ---------- f32 <-> bf16 helpers (bit-level, RNE) ----------
__device__ __forceinline__ ushort f2bf(float f) {
    uint32_t u = __float_as_uint(f);
    uint32_t r = (u + 0x7FFFu + ((u >> 16) & 1u)) >> 16;
    return (ushort)r;
}
__device__ __forceinline__ float bf2f(ushort b) {
    return __uint_as_float(((uint32_t)b) << 16);
}
__device__ __forceinline__ void split1(float v, ushort& h, ushort& l) {
    ushort hb = f2bf(v);
    float hf = bf2f(hb);
    h = hb;
    l = f2bf(v - hf);
}

// ---------- split f32 -> (hi, lo) bf16 arrays ----------
__global__ __launch_bounds__(256) void split_kernel(const float* __restrict__ x,
                                                    ushort* __restrict__ hi,
                                                    ushort* __restrict__ lo, int n4) {
    int i = blockIdx.x * blockDim.x + threadIdx.x;
    int stride = gridDim.x * blockDim.x;
    for (; i < n4; i += stride) {
        float4 v = reinterpret_cast<const float4*>(x)[i];
        ushort4 h, l;
        split1(v.x, h.x, l.x);
        split1(v.y, h.y, l.y);
        split1(v.z, h.z, l.z);
        split1(v.w, h.w, l.w);
        reinterpret_cast<ushort4*>(hi)[i] = h;
        reinterpret_cast<ushort4*>(lo)[i] = l;
    }
}

// ---------- GRU step body (one timestep, one layer) ----------
// 256 blocks per layer, 256 threads = 4 units x 64 batches; block handles 4 H-units.
// LAYER 0: gi = gather of W_ih columns at token. LAYER 1: gi = W_ih * x_in (matvec).
template <int LAYER>
__device__ __forceinline__ void gru_body(
    const float* __restrict__ h_in,   // (B,H)
    float* __restrict__ h_out,        // (B,H)
    const float* __restrict__ W_hh,   // (3H,H)
    const float* __restrict__ b_hh,   // (3H)
    const float* __restrict__ W_ih,   // L0: (3H,V)  L1: (3H,H)
    const float* __restrict__ b_ih,   // (3H)
    const int* __restrict__ tok,      // L0: B ints (step-offset applied by caller)
    const float* __restrict__ x_in,   // L1: (B,H)
    ushort* __restrict__ yh,          // L1: bf16 hi of h_out (step-offset applied)
    ushort* __restrict__ yl,          // L1: bf16 lo of h_out
    int blk,
    float (*hl_s)[68], float (*xl_s)[68])
{
    const int tid = threadIdx.x;
    const int u = tid & 3;
    const int b = tid >> 2;
    const int j = blk * 4 + u;

    const int sr = tid >> 2;  // staging row
    const int sq = tid & 3;   // staging quarter (16 floats each)

    float ahr = 0.f, ahz = 0.f, ahn = 0.f;
    float air = 0.f, aiz = 0.f, ain = 0.f;

    const float* Wr = W_hh + (size_t)j * HH;
    const float* Wz = W_hh + (size_t)(HH + j) * HH;
    const float* Wn = W_hh + (size_t)(2 * HH + j) * HH;
    const float* Ur = nullptr;
    const float* Uz = nullptr;
    const float* Un = nullptr;
    if constexpr (LAYER == 1) {
        Ur = W_ih + (size_t)j * HH;
        Uz = W_ih + (size_t)(HH + j) * HH;
        Un = W_ih + (size_t)(2 * HH + j) * HH;
    }

    for (int kk = 0; kk < HH; kk += 64) {
        // cooperative stage of h[:, kk:kk+64] (and x for layer 1)
        const float4* hs = reinterpret_cast<const float4*>(h_in + (size_t)sr * HH + kk + sq * 16);
        float4 a0 = hs[0], a1 = hs[1], a2 = hs[2], a3 = hs[3];
        *reinterpret_cast<float4*>(&hl_s[sr][sq * 16 + 0])  = a0;
        *reinterpret_cast<float4*>(&hl_s[sr][sq * 16 + 4])  = a1;
        *reinterpret_cast<float4*>(&hl_s[sr][sq * 16 + 8])  = a2;
        *reinterpret_cast<float4*>(&hl_s[sr][sq * 16 + 12]) = a3;
        if constexpr (LAYER == 1) {
            const float4* xs = reinterpret_cast<const float4*>(x_in + (size_t)sr * HH + kk + sq * 16);
            float4 c0 = xs[0], c1 = xs[1], c2 = xs[2], c3 = xs[3];
            *reinterpret_cast<float4*>(&xl_s[sr][sq * 16 + 0])  = c0;
            *reinterpret_cast<float4*>(&xl_s[sr][sq * 16 + 4])  = c1;
            *reinterpret_cast<float4*>(&xl_s[sr][sq * 16 + 8])  = c2;
            *reinterpret_cast<float4*>(&xl_s[sr][sq * 16 + 12]) = c3;
        }
        __syncthreads();

#pragma unroll
        for (int k = 0; k < 64; k += 4) {
            float4 hv = *reinterpret_cast<const float4*>(&hl_s[b][k]);
            float4 wr = *reinterpret_cast<const float4*>(Wr + kk + k);
            float4 wz = *reinterpret_cast<const float4*>(Wz + kk + k);
            float4 wn = *reinterpret_cast<const float4*>(Wn + kk + k);
            ahr += hv.x * wr.x + hv.y * wr.y + hv.z * wr.z + hv.w * wr.w;
            ahz += hv.x * wz.x + hv.y * wz.y + hv.z * wz.z + hv.w * wz.w;
            ahn += hv.x * wn.x + hv.y * wn.y + hv.z * wn.z + hv.w * wn.w;
            if constexpr (LAYER == 1) {
                float4 xv = *reinterpret_cast<const float4*>(&xl_s[b][k]);
                float4 ur = *reinterpret_cast<const float4*>(Ur + kk + k);
                float4 uz = *reinterpret_cast<const float4*>(Uz + kk + k);
                float4 un = *reinterpret_cast<const float4*>(Un + kk + k);
                air += xv.x * ur.x + xv.y * ur.y + xv.z * ur.z + xv.w * ur.w;
                aiz += xv.x * uz.x + xv.y * uz.y + xv.z * uz.z + xv.w * uz.w;
                ain += xv.x * un.x + xv.y * un.y + xv.z * un.z + xv.w * un.w;
            }
        }
        __syncthreads();
    }

    float gir, giz, gin;
    if constexpr (LAYER == 0) {
        int v = tok[b];
        gir = W_ih[(size_t)j * VV + v];
        giz = W_ih[(size_t)(HH + j) * VV + v];
        gin = W_ih[(size_t)(2 * HH + j) * VV + v];
    } else {
        gir = air; giz = aiz; gin = ain;
    }
    gir += b_ih[j];
    giz += b_ih[HH + j];
    gin += b_ih[2 * HH + j];
    float ghr = ahr + b_hh[j];
    float ghz = ahz + b_hh[HH + j];
    float ghn = ahn + b_hh[2 * HH + j];

    float rg = 1.0f / (1.0f + expf(-(gir + ghr)));
    float zg = 1.0f / (1.0f + expf(-(giz + ghz)));
    float ng = tanhf(gin + rg * ghn);
    float hp = h_in[(size_t)b * HH + j];
    float hnew = (1.0f - zg) * ng + zg * hp;
    h_out[(size_t)b * HH + j] = hnew;
    if constexpr (LAYER == 1) {
        ushort hb, lb;
        split1(hnew, hb, lb);
        yh[b * HH + j] = hb;
        yl[b * HH + j] = lb;
    }
}

// Fused pipelined step: blocks 0..255 run layer0 step t, blocks 256..511 run
// layer1 step t-1 (which consumes ys0[t-1] written by the PREVIOUS launch).
__global__ __launch_bounds__(256) void gru_fused(
    int t,
    const int* __restrict__ tok_all,   // (T,B)
    const float* __restrict__ hidden,  // (L,B,H)
    const float* __restrict__ W_ih0, const float* __restrict__ W_hh0,
    const float* __restrict__ b_ih0, const float* __restrict__ b_hh0,
    const float* __restrict__ W_ih1, const float* __restrict__ W_hh1,
    const float* __restrict__ b_ih1, const float* __restrict__ b_hh1,
    float* __restrict__ ys0,           // (T,B,H)
    const float* __restrict__ h1_in,   // (B,H) layer1 input hidden for step t-1
    float* __restrict__ h1_out,        // (B,H) layer1 output hidden for step t-1
    ushort* __restrict__ ys1h,         // already offset to step t-1
    ushort* __restrict__ ys1l)
{
    __shared__ float hl_s[64][68];
    __shared__ float xl_s[64][68];
    const size_t BH = (size_t)BB * HH;

    if (blockIdx.x < 256) {
        if (t >= TT) return;
        const float* hin = (t == 0) ? hidden : ys0 + (size_t)(t - 1) * BH;
        gru_body<0>(hin, ys0 + (size_t)t * BH, W_hh0, b_hh0, W_ih0, b_ih0,
                    tok_all + (size_t)t * BB, nullptr, nullptr, nullptr,
                    blockIdx.x, hl_s, xl_s);
    } else {
        if (t < 1) return;
        gru_body<1>(h1_in, h1_out, W_hh1, b_hh1, W_ih1, b_ih1,
                    nullptr, ys0 + (size_t)(t - 1) * BH, ys1h, ys1l,
                    blockIdx.x - 256, hl_s, xl_s);
    }
}

// ---------- logits GEMM: C(MxN) = A(MxK) * B^T(NxK) + bias, bf16x3 split MFMA ----------
// Tile 128x128, BK=32, 256 threads (4 waves, 2x2 of 64x64), LDS rows padded +8 bf16.
__global__ __launch_bounds__(256) void gemm_logits(
    const ushort* __restrict__ Ah, const ushort* __restrict__ Al,
    const ushort* __restrict__ Bh, const ushort* __restrict__ Bl,
    const float* __restrict__ bias, float* __restrict__ C,
    int M, int N, int K)
{
    const int LDT = 40;  // 32 + 8 pad (bf16 elems)
    __shared__ ushort Alh[128 * 40];
    __shared__ ushort All[128 * 40];
    __shared__ ushort Blh[128 * 40];
    __shared__ ushort Bll[128 * 40];

    const int tid = threadIdx.x;
    const int bid = blockIdx.x;
    const int mtiles = M / 128;
    const int m0 = (bid % mtiles) * 128;
    const int n0 = (bid / mtiles) * 128;

    const int wid = tid >> 6;
    const int lane = tid & 63;
    const int wm = (wid >> 1) * 64;  // wave row base within tile
    const int wn = (wid & 1) * 64;   // wave col base within tile
    const int lrow = lane & 15;
    const int lq = lane >> 4;  // k-group 0..3

    // staging coords: 512 chunks of 8 bf16; this thread handles chunks tid and tid+256
    const int r0 = tid >> 2, q0 = tid & 3;
    const int r1 = (tid + 256) >> 2, q1 = (tid + 256) & 3;

    f32x4 zero = {0.f, 0.f, 0.f, 0.f};
    f32x4 acc[4][4];
#pragma unroll
    for (int i = 0; i < 4; ++i)
#pragma unroll
        for (int jn = 0; jn < 4; ++jn) acc[i][jn] = zero;

    for (int kk = 0; kk < K; kk += 32) {
        uint4 va0 = *reinterpret_cast<const uint4*>(Ah + (size_t)(m0 + r0) * K + kk + q0 * 8);
        uint4 va1 = *reinterpret_cast<const uint4*>(Ah + (size_t)(m0 + r1) * K + kk + q1 * 8);
        uint4 vb0 = *reinterpret_cast<const uint4*>(Al + (size_t)(m0 + r0) * K + kk + q0 * 8);
        uint4 vb1 = *reinterpret_cast<const uint4*>(Al + (size_t)(m0 + r1) * K + kk + q1 * 8);
        uint4 vc0 = *reinterpret_cast<const uint4*>(Bh + (size_t)(n0 + r0) * K + kk + q0 * 8);
        uint4 vc1 = *reinterpret_cast<const uint4*>(Bh + (size_t)(n0 + r1) * K + kk + q1 * 8);
        uint4 vd0 = *reinterpret_cast<const uint4*>(Bl + (size_t)(n0 + r0) * K + kk + q0 * 8);
        uint4 vd1 = *reinterpret_cast<const uint4*>(Bl + (size_t)(n0 + r1) * K + kk + q1 * 8);
        __syncthreads();  // previous iteration's frag reads complete
        *reinterpret_cast<uint4*>(&Alh[r0 * LDT + q0 * 8]) = va0;
        *reinterpret_cast<uint4*>(&Alh[r1 * LDT + q1 * 8]) = va1;
        *reinterpret_cast<uint4*>(&All[r0 * LDT + q0 * 8]) = vb0;
        *reinterpret_cast<uint4*>(&All[r1 * LDT + q1 * 8]) = vb1;
        *reinterpret_cast<uint4*>(&Blh[r0 * LDT + q0 * 8]) = vc0;
        *reinterpret_cast<uint4*>(&Blh[r1 * LDT + q1 * 8]) = vc1;
        *reinterpret_cast<uint4*>(&Bll[r0 * LDT + q0 * 8]) = vd0;
        *reinterpret_cast<uint4*>(&Bll[r1 * LDT + q1 * 8]) = vd1;
        __syncthreads();

        bf16x8 afh[4], afl[4], bfh[4], bfl[4];
#pragma unroll
        for (int i = 0; i < 4; ++i) {
            afh[i] = *reinterpret_cast<const bf16x8*>(&Alh[(wm + i * 16 + lrow) * LDT + lq * 8]);
            afl[i] = *reinterpret_cast<const bf16x8*>(&All[(wm + i * 16 + lrow) * LDT + lq * 8]);
            bfh[i] = *reinterpret_cast<const bf16x8*>(&Blh[(wn + i * 16 + lrow) * LDT + lq * 8]);
            bfl[i] = *reinterpret_cast<const bf16x8*>(&Bll[(wn + i * 16 + lrow) * LDT + lq * 8]);
        }
#pragma unroll
        for (int i = 0; i < 4; ++i) {
#pragma unroll
            for (int jn = 0; jn < 4; ++jn) {
                acc[i][jn] = __builtin_amdgcn_mfma_f32_16x16x32_bf16(afh[i], bfh[jn], acc[i][jn], 0, 0, 0);
                acc[i][jn] = __builtin_amdgcn_mfma_f32_16x16x32_bf16(afh[i], bfl[jn], acc[i][jn], 0, 0, 0);
                acc[i][jn] = __builtin_amdgcn_mfma_f32_16x16x32_bf16(afl[i], bfh[jn], acc[i][jn], 0, 0, 0);
            }
        }
    }

    // epilogue: C/D frag mapping col = lane&15, row = (lane>>4)*4 + reg
#pragma unroll
    for (int i = 0; i < 4; ++i) {
#pragma unroll
        for (int jn = 0; jn < 4; ++jn) {
            int cn = n0 + wn + jn * 16 + lrow;
            float bv = bias[cn];
#pragma unroll
            for (int rr = 0; rr < 4; ++rr) {
                int cm = m0 + wm + i * 16 + lq * 4 + rr;
                C[(size_t)cm * N + cn] = acc[i][jn][rr] + bv;
            }
        }
    }
}

extern "C" void kernel_launch(void* const* d_in, const int* in_sizes, int n_in,
                              void* d_out, int out_size, void* d_ws, size_t ws_size,
                              hipStream_t stream) {
    const int*   tok    = (const int*)d_in[0];
    const float* hidden = (const float*)d_in[1];
    const float* W_ih0  = (const float*)d_in[2];
    const float* W_hh0  = (const float*)d_in[3];
    const float* b_ih0  = (const float*)d_in[4];
    const float* b_hh0  = (const float*)d_in[5];
    const float* W_ih1  = (const float*)d_in[6];
    const float* W_hh1  = (const float*)d_in[7];
    const float* b_ih1  = (const float*)d_in[8];
    const float* b_hh1  = (const float*)d_in[9];
    const float* W_out  = (const float*)d_in[10];
    const float* b_out  = (const float*)d_in[11];
    float* out = (float*)d_out;

    const size_t SEQ = (size_t)TT * BB * HH;  // 16,777,216
    const size_t BH  = (size_t)BB * HH;       // 65,536
    float*  ys0   = (float*)d_ws;                    // SEQ f32       (64 MB)
    float*  h1a   = ys0 + SEQ;                       // BH f32        (256 KB)
    float*  h1b   = h1a + BH;                        // BH f32        (256 KB)
    ushort* ys1h  = (ushort*)(h1b + BH);             // SEQ bf16      (32 MB)
    ushort* ys1l  = ys1h + SEQ;                      // SEQ bf16      (32 MB)
    ushort* wouth = ys1l + SEQ;                      // V*H bf16      (16 MB)
    ushort* woutl = wouth + (size_t)VV * HH;         // V*H bf16      (16 MB)
    // total ws use: ~161 MB

    // split W_out into bf16 hi/lo (independent of recurrence; runs up front)
    split_kernel<<<2048, 256, 0, stream>>>(W_out, wouth, woutl, (VV * HH) / 4);

    // pipelined recurrence: launch t runs L0 step t and L1 step t-1
    for (int t = 0; t <= TT; ++t) {
        const int s = t - 1;  // layer-1 step index
        const float* h1_in  = (s <= 0) ? hidden + BH : ((s & 1) ? h1a : h1b);
        float*       h1_out = (s >= 0 && (s & 1)) ? h1b : h1a;
        ushort* yh = ys1h + (size_t)(s < 0 ? 0 : s) * BH;
        ushort* yl = ys1l + (size_t)(s < 0 ? 0 : s) * BH;
        gru_fused<<<512, 256, 0, stream>>>(t, tok, hidden,
                                           W_ih0, W_hh0, b_ih0, b_hh0,
                                           W_ih1, W_hh1, b_ih1, b_hh1,
                                           ys0, h1_in, h1_out, yh, yl);
    }

    // logits = ys1 @ W_out^T + b_out   (bf16x3 split MFMA)
    gemm_logits<<<(TT * BB / 128) * (VV / 128), 256, 0, stream>>>(
        ys1h, ys1l, wouth, woutl, b_out, out, TT * BB, VV, HH);

    // new_hidden = [h0_T, h1_T];  h1_T lives in the (TT-1)-parity buffer = h1b
    hipMemcpyAsync(out + (size_t)TT * BB * VV, ys0 + (size_t)(TT - 1) * BH,
                   BH * sizeof(float), hipMemcpyDeviceToDevice, stream);
    hipMemcpyAsync(out + (size_t)TT * BB * VV + BH, h1b,
                   BH * sizeof(float), hipMemcpyDeviceToDevice, stream);
}